// Round 22
// baseline (429.126 us; speedup 1.0000x reference)
//
#include <hip/hip_runtime.h>

typedef __attribute__((ext_vector_type(8))) short bf16x8;
typedef __attribute__((ext_vector_type(4))) float f32x4;
typedef __attribute__((ext_vector_type(4))) unsigned int u32x4;
typedef __attribute__((ext_vector_type(2))) unsigned int u32x2;
typedef unsigned short u16;
typedef unsigned int u32;

__device__ __forceinline__ u16 f2bf(float f) {
    union { float f; u32 u; } c; c.f = f;
    return (u16)((c.u + 0x7FFFu + ((c.u >> 16) & 1u)) >> 16);
}

__device__ __forceinline__ bf16x8 ld16(const void* p) {
    union { uint4 u; bf16x8 v; } c;
    c.u = *reinterpret_cast<const uint4*>(p);
    return c.v;
}

__device__ __forceinline__ u32 cvtpk(float lo, float hi) {
    u32 r;
    asm("v_cvt_pk_bf16_f32 %0, %1, %2" : "=v"(r) : "v"(lo), "v"(hi));
    return r;
}

// ---------------- prep: transpose weights to bf16, n-major k-contig ----------
__global__ void prep_kernel(const float* __restrict__ wqkv, const float* __restrict__ wproj,
                            u16* __restrict__ Wqt, u16* __restrict__ Wpt) {
    int idx = blockIdx.x * 256 + threadIdx.x;
    if (idx < 6 * 192 * 384) {
        int k = idx % 384;
        int n = idx / 384;
        int h = n / 192, dd = n % 192;
        Wqt[idx] = f2bf(wqkv[(h * 384 + k) * 192 + dd]);
    }
    if (idx < 384 * 384) {
        int k = idx % 384, n = idx / 384;
        Wpt[idx] = f2bf(wproj[k * 384 + n]);
    }
}

// ---------------- LayerNorm: (131072,384) f32 -> bf16 -----------------------
__global__ __launch_bounds__(256) void ln_kernel(const float* __restrict__ x,
                                                 const float* __restrict__ gamma,
                                                 const float* __restrict__ beta,
                                                 u16* __restrict__ xln) {
    int row = blockIdx.x * 4 + (threadIdx.x >> 6);
    int l = threadIdx.x & 63;
    const float* xr = x + (size_t)row * 384;
    float2 v[3];
    float s = 0.f, sq = 0.f;
#pragma unroll
    for (int i = 0; i < 3; ++i) {
        v[i] = *reinterpret_cast<const float2*>(xr + i * 128 + l * 2);
        s += v[i].x + v[i].y;
        sq += v[i].x * v[i].x + v[i].y * v[i].y;
    }
#pragma unroll
    for (int m = 1; m < 64; m <<= 1) {
        s += __shfl_xor(s, m, 64);
        sq += __shfl_xor(sq, m, 64);
    }
    float mean = s * (1.0f / 384.0f);
    float var = sq * (1.0f / 384.0f) - mean * mean;
    float rstd = rsqrtf(var + 1e-5f);
#pragma unroll
    for (int i = 0; i < 3; ++i) {
        int c = i * 128 + l * 2;
        float y0 = (v[i].x - mean) * rstd * gamma[c] + beta[c];
        float y1 = (v[i].y - mean) * rstd * gamma[c + 1] + beta[c + 1];
        u32 packed = (u32)f2bf(y0) | ((u32)f2bf(y1) << 16);
        *reinterpret_cast<u32*>(xln + (size_t)row * 384 + c) = packed;
    }
}

// ---------------- QKV GEMM: BK=32, 40KB LDS dbuf, (row>>1) swizzle ----------
// grid (1024, 6): x=mt, y=h. 256 thr, 4 waves, wave 64x96, 3 blocks/CU.
// NOTE: launch_bounds(256,4) triple-confirmed to spill; keep (256,3).
__global__ __launch_bounds__(256, 3) void qkv_kernel(const u16* __restrict__ xln,
                                                     const u16* __restrict__ Wqt,
                                                     u16* __restrict__ qkvout) {
    __shared__ u16 As[2][128 * 32];   // 2 x 8 KB
    __shared__ u16 Bs[2][192 * 32];   // 2 x 12 KB -> total 40 KB
    const int mt = blockIdx.x;
    const int h = blockIdx.y;
    const int t = threadIdx.x;
    const int l = t & 63, w = t >> 6;
    const int wm = w >> 1, wn = w & 1;
    const int l15 = l & 15, lq = l >> 4;
    const int rloc = l >> 2;
    const int m0 = mt * 128;
    const u16* Ag = xln + (size_t)m0 * 384;
    const u16* Bg = Wqt + (size_t)h * 192 * 384;
    f32x4 acc[4][6];
#pragma unroll
    for (int rg = 0; rg < 4; ++rg)
#pragma unroll
        for (int cg = 0; cg < 6; ++cg) acc[rg][cg] = (f32x4){0.f, 0.f, 0.f, 0.f};

    auto stage = [&](int kt, int buf) {
#pragma unroll
        for (int i = 0; i < 2; ++i) {
            int row = w * 32 + i * 16 + rloc;
            int ss = (l & 3) ^ ((row >> 1) & 3);
            __builtin_amdgcn_global_load_lds(Ag + (size_t)row * 384 + kt * 32 + ss * 8,
                                             &As[buf][(w * 32 + i * 16) * 32], 16, 0, 0);
        }
#pragma unroll
        for (int i = 0; i < 3; ++i) {
            int row = w * 48 + i * 16 + rloc;
            int ss = (l & 3) ^ ((row >> 1) & 3);
            __builtin_amdgcn_global_load_lds(Bg + (size_t)row * 384 + kt * 32 + ss * 8,
                                             &Bs[buf][(w * 48 + i * 16) * 32], 16, 0, 0);
        }
    };

    stage(0, 0);
    __syncthreads();

    for (int kt = 0; kt < 12; ++kt) {
        const int cur = kt & 1;
        if (kt < 11) stage(kt + 1, cur ^ 1);
        char* Ab = reinterpret_cast<char*>(As[cur]);
        char* Bb = reinterpret_cast<char*>(Bs[cur]);
        bf16x8 af[4], bf[6];
#pragma unroll
        for (int rg = 0; rg < 4; ++rg) {
            int row = wm * 64 + rg * 16 + l15;
            af[rg] = ld16(Ab + row * 64 + ((lq ^ ((row >> 1) & 3)) << 4));
        }
#pragma unroll
        for (int cg = 0; cg < 6; ++cg) {
            int row = wn * 96 + cg * 16 + l15;
            bf[cg] = ld16(Bb + row * 64 + ((lq ^ ((row >> 1) & 3)) << 4));
        }
#pragma unroll
        for (int rg = 0; rg < 4; ++rg)
#pragma unroll
            for (int cg = 0; cg < 6; ++cg)
                acc[rg][cg] = __builtin_amdgcn_mfma_f32_16x16x32_bf16(af[rg], bf[cg], acc[rg][cg], 0, 0, 0);
        __syncthreads();
    }
    const int b = m0 >> 8;
    const int s0 = m0 & 255;
    u16* out = qkvout + ((size_t)(b * 6 + h) * 256) * 192;
#pragma unroll
    for (int rg = 0; rg < 4; ++rg)
#pragma unroll
        for (int cg = 0; cg < 6; ++cg)
#pragma unroll
            for (int r = 0; r < 4; ++r) {
                int s = s0 + wm * 64 + rg * 16 + lq * 4 + r;
                int dd = wn * 96 + cg * 16 + l15;
                out[(size_t)s * 192 + dd] = f2bf(acc[rg][cg][r]);
            }
}

// ---------------- Attention: swapped QK^T + s_setprio on MFMA clusters ------
__global__ __launch_bounds__(512, 2) void attn_kernel(const u16* __restrict__ qkv,
                                                      u16* __restrict__ aout) {
    __shared__ u16 Ks[256 * 64];      // 32 KB
    __shared__ u16 Vt[64 * 256];      // 32 KB
    __shared__ u16 Ps[8 * 16 * 32];   // 8 KB -> total 72 KB
    const int bh = blockIdx.x;
    const int b = bh / 6, h = bh % 6;
    const u16* base = qkv + (size_t)bh * (256 * 192);
    const int t = threadIdx.x;
    const int w = t >> 6, l = t & 63;
    const int l15 = l & 15, lq = l >> 4;

#pragma unroll
    for (int i = 0; i < 4; ++i) {
        int u = t + 512 * i;
        int row = u >> 3, seg = u & 7;
        uint4 v = *reinterpret_cast<const uint4*>(base + row * 192 + 64 + seg * 8);
        *reinterpret_cast<uint4*>(reinterpret_cast<char*>(Ks) + row * 128 + ((seg * 16) ^ ((row & 7) << 4))) = v;
    }
    {
        int j = t >> 1, d0 = (t & 1) * 32;
#pragma unroll
        for (int c = 0; c < 4; ++c) {
            uint4 v = *reinterpret_cast<const uint4*>(base + j * 192 + 128 + d0 + c * 8);
            const u16* pv = reinterpret_cast<const u16*>(&v);
#pragma unroll
            for (int e = 0; e < 8; ++e) {
                int d = d0 + c * 8 + e;
                *reinterpret_cast<u16*>(reinterpret_cast<char*>(Vt) + d * 512 + ((j * 2) ^ ((d & 7) << 4))) = pv[e];
            }
        }
    }
    const int qrow0 = w * 16;
    const int qrow1 = (15 - w) * 16;
    const int kbmax0 = w >> 2;
    const int kbmax1 = (15 - w) >> 2;
    bf16x8 qf[2][2];
#pragma unroll
    for (int kk = 0; kk < 2; ++kk) {
        qf[0][kk] = ld16(base + (qrow0 + l15) * 192 + kk * 32 + lq * 8);
        qf[1][kk] = ld16(base + (qrow1 + l15) * 192 + kk * 32 + lq * 8);
    }
    __syncthreads();

    f32x4 acc[2][4];
#pragma unroll
    for (int rg = 0; rg < 2; ++rg)
#pragma unroll
        for (int dg = 0; dg < 4; ++dg) acc[rg][dg] = (f32x4){0.f, 0.f, 0.f, 0.f};
    float l_r[2] = {0.f, 0.f};

    const float CEXP = 0.18033688011112042f;  // 0.125 * log2(e)
    char* pbase = reinterpret_cast<char*>(Ps) + w * 1024;
    auto fs = [](int row) { return ((row + (row >> 2)) & 3) << 4; };
    const int myfs = fs(l15);

    for (int kb = 0; kb <= kbmax1; ++kb) {
        const bool do0 = (kb <= kbmax0);
        f32x4 sc[2][4];
#pragma unroll
        for (int rg = 0; rg < 2; ++rg)
#pragma unroll
            for (int cg = 0; cg < 4; ++cg) sc[rg][cg] = (f32x4){0.f, 0.f, 0.f, 0.f};
#pragma unroll
        for (int kk = 0; kk < 2; ++kk) {
            bf16x8 kf[4];
#pragma unroll
            for (int cg = 0; cg < 4; ++cg) {
                int krow = kb * 64 + cg * 16 + l15;
                kf[cg] = ld16(reinterpret_cast<char*>(Ks) + krow * 128 + ((kk * 64 + lq * 16) ^ ((krow & 7) << 4)));
            }
            __builtin_amdgcn_s_setprio(1);
            if (do0)
#pragma unroll
                for (int cg = 0; cg < 4; ++cg)
                    sc[0][cg] = __builtin_amdgcn_mfma_f32_16x16x32_bf16(kf[cg], qf[0][kk], sc[0][cg], 0, 0, 0);
#pragma unroll
            for (int cg = 0; cg < 4; ++cg)
                sc[1][cg] = __builtin_amdgcn_mfma_f32_16x16x32_bf16(kf[cg], qf[1][kk], sc[1][cg], 0, 0, 0);
            __builtin_amdgcn_s_setprio(0);
        }
#pragma unroll
        for (int rg = 0; rg < 2; ++rg) {
            if (rg == 0 && !do0) continue;
            const int qb = rg ? qrow1 : qrow0;
            const int diag = rg ? kbmax1 : kbmax0;
            if (kb == diag) {
                int gq = qb + l15;
#pragma unroll
                for (int cg = 0; cg < 4; ++cg)
#pragma unroll
                    for (int r = 0; r < 4; ++r) {
                        int gk = kb * 64 + cg * 16 + lq * 4 + r;
                        if (gk > gq) sc[rg][cg][r] = -3.0e38f;
                    }
            }
#pragma unroll
            for (int cg = 0; cg < 4; ++cg)
#pragma unroll
                for (int r = 0; r < 4; ++r)
                    sc[rg][cg][r] = exp2f(sc[rg][cg][r] * CEXP);
            float s = ((sc[rg][0][0] + sc[rg][0][1]) + (sc[rg][0][2] + sc[rg][0][3]))
                    + ((sc[rg][1][0] + sc[rg][1][1]) + (sc[rg][1][2] + sc[rg][1][3]))
                    + ((sc[rg][2][0] + sc[rg][2][1]) + (sc[rg][2][2] + sc[rg][2][3]))
                    + ((sc[rg][3][0] + sc[rg][3][1]) + (sc[rg][3][2] + sc[rg][3][3]));
            s += __shfl_xor(s, 16, 64);
            s += __shfl_xor(s, 32, 64);
            l_r[rg] += s;
            u32 pk0[4], pk1[4];
#pragma unroll
            for (int cg = 0; cg < 4; ++cg) {
                pk0[cg] = cvtpk(sc[rg][cg][0], sc[rg][cg][1]);
                pk1[cg] = cvtpk(sc[rg][cg][2], sc[rg][cg][3]);
            }
#pragma unroll
            for (int kk = 0; kk < 2; ++kk) {
#pragma unroll
                for (int c2 = 0; c2 < 2; ++c2) {
                    int cg = kk * 2 + c2;
                    u32x2 wv;
                    wv.x = pk0[cg];
                    wv.y = pk1[cg];
                    *reinterpret_cast<u32x2*>(pbase + l15 * 64 + ((c2 * 32 + lq * 8) ^ myfs)) = wv;
                }
                bf16x8 pf = ld16(pbase + l15 * 64 + ((lq * 16) ^ myfs));
                bf16x8 vf[4];
#pragma unroll
                for (int dg = 0; dg < 4; ++dg) {
                    int d = dg * 16 + l15;
                    vf[dg] = ld16(reinterpret_cast<char*>(Vt) + d * 512 + ((kb * 128 + kk * 64 + lq * 16) ^ ((d & 7) << 4)));
                }
                __builtin_amdgcn_s_setprio(1);
#pragma unroll
                for (int dg = 0; dg < 4; ++dg)
                    acc[rg][dg] = __builtin_amdgcn_mfma_f32_16x16x32_bf16(pf, vf[dg], acc[rg][dg], 0, 0, 0);
                __builtin_amdgcn_s_setprio(0);
            }
        }
    }
#pragma unroll
    for (int rg = 0; rg < 2; ++rg) {
        const int qb = rg ? qrow1 : qrow0;
#pragma unroll
        for (int r = 0; r < 4; ++r) {
            float lr = __shfl(l_r[rg], lq * 4 + r, 64);
            float inv = 1.0f / lr;
            int gq = qb + lq * 4 + r;
            u16* orow = aout + ((size_t)b * 256 + gq) * 384 + h * 64;
#pragma unroll
            for (int dg = 0; dg < 4; ++dg) orow[dg * 16 + l15] = f2bf(acc[rg][dg][r] * inv);
        }
    }
}

// ---------------- Proj GEMM: gload_lds 2-phase + LDS-assembled nt epilogue --
__global__ __launch_bounds__(256, 2) void proj_kernel(const u16* __restrict__ A,
                                                      const u16* __restrict__ Wpt,
                                                      const float* __restrict__ bias,
                                                      float* __restrict__ out) {
    __shared__ u16 S[32768];  // 64 KB: As dbuf 2x8192, Bs dbuf 2x8192
    u16* Asb[2] = {S, S + 8192};
    u16* Bsb[2] = {S + 16384, S + 24576};
    const int mt = blockIdx.x;
    const int nt = blockIdx.y;
    const int t = threadIdx.x;
    const int l = t & 63, w = t >> 6;
    const int wm = w >> 1, wn = w & 1;
    const int l15 = l & 15, lq = l >> 4;
    const int rloc = l >> 3, seg = l & 7;
    const int m0 = mt * 128;
    const u16* Ag = A + (size_t)m0 * 384;
    const u16* Bg = Wpt + (size_t)nt * 128 * 384;
    f32x4 acc[4][4];
#pragma unroll
    for (int rg = 0; rg < 4; ++rg)
#pragma unroll
        for (int cg = 0; cg < 4; ++cg) acc[rg][cg] = (f32x4){0.f, 0.f, 0.f, 0.f};

    auto stage = [&](int kt, int buf) {
#pragma unroll
        for (int i = 0; i < 4; ++i) {
            int row = w * 32 + i * 8 + rloc;
            int ss = seg ^ (row & 7);
            __builtin_amdgcn_global_load_lds(Ag + (size_t)row * 384 + kt * 64 + ss * 8,
                                             &Asb[buf][(w * 32 + i * 8) * 64], 16, 0, 0);
            __builtin_amdgcn_global_load_lds(Bg + (size_t)row * 384 + kt * 64 + ss * 8,
                                             &Bsb[buf][(w * 32 + i * 8) * 64], 16, 0, 0);
        }
    };

    stage(0, 0);
    __syncthreads();

    for (int kt = 0; kt < 6; ++kt) {
        const int cur = kt & 1;
        if (kt < 5) stage(kt + 1, cur ^ 1);
        char* Ab = reinterpret_cast<char*>(Asb[cur]);
        char* Bb = reinterpret_cast<char*>(Bsb[cur]);
        bf16x8 af[4][2], bf[4][2];
#pragma unroll
        for (int rg = 0; rg < 4; ++rg)
#pragma unroll
            for (int kk = 0; kk < 2; ++kk) {
                int row = wm * 64 + rg * 16 + l15;
                af[rg][kk] = ld16(Ab + row * 128 + ((kk * 64 + lq * 16) ^ ((row & 7) << 4)));
            }
#pragma unroll
        for (int cg = 0; cg < 4; ++cg)
#pragma unroll
            for (int kk = 0; kk < 2; ++kk) {
                int row = wn * 64 + cg * 16 + l15;
                bf[cg][kk] = ld16(Bb + row * 128 + ((kk * 64 + lq * 16) ^ ((row & 7) << 4)));
            }
#pragma unroll
        for (int kk = 0; kk < 2; ++kk)
#pragma unroll
            for (int rg = 0; rg < 4; ++rg)
#pragma unroll
                for (int cg = 0; cg < 4; ++cg)
                    acc[rg][cg] = __builtin_amdgcn_mfma_f32_16x16x32_bf16(af[rg][kk], bf[cg][kk], acc[rg][cg], 0, 0, 0);
        __syncthreads();
    }
    float* ftile = reinterpret_cast<float*>(S);
#pragma unroll
    for (int rg = 0; rg < 4; ++rg)
#pragma unroll
        for (int cg = 0; cg < 4; ++cg) {
            int n_loc = wn * 64 + cg * 16 + l15;
            float bv = bias[nt * 128 + n_loc];
#pragma unroll
            for (int r = 0; r < 4; ++r) {
                int m_loc = wm * 64 + rg * 16 + lq * 4 + r;
                ftile[m_loc * 128 + n_loc] = acc[rg][cg][r] + bv;
            }
        }
    __syncthreads();
    float* outp = out + (size_t)m0 * 384 + nt * 128;
#pragma unroll
    for (int i = 0; i < 16; ++i) {
        int idx = t + 256 * i;
        int row = idx >> 5;
        int c = (idx & 31) * 4;
        u32x4 v = *reinterpret_cast<const u32x4*>(ftile + row * 128 + c);
        __builtin_nontemporal_store(v, reinterpret_cast<u32x4*>(outp + (size_t)row * 384 + c));
    }
}

extern "C" void kernel_launch(void* const* d_in, const int* in_sizes, int n_in,
                              void* d_out, int out_size, void* d_ws, size_t ws_size,
                              hipStream_t stream) {
    const float* logits = (const float*)d_in[0];
    const float* gamma  = (const float*)d_in[1];
    const float* beta   = (const float*)d_in[2];
    const float* wqkv   = (const float*)d_in[3];
    const float* wproj  = (const float*)d_in[4];
    const float* bproj  = (const float*)d_in[5];
    float* out = (float*)d_out;

    char* ws = (char*)d_ws;
    u16* Wqt  = (u16*)(ws);                    //   884736 B
    u16* Wpt  = (u16*)(ws + 884736);           //   294912 B
    u16* xln  = (u16*)(ws + 1179648);          // 100663296 B
    u16* qkvb = (u16*)(ws + 101842944);        // 301989888 B -> total 403832832 B
    u16* attnout = xln;                        // alias: xln dead after qkv gemm

    hipLaunchKernelGGL(prep_kernel, dim3(1728), dim3(256), 0, stream, wqkv, wproj, Wqt, Wpt);
    hipLaunchKernelGGL(ln_kernel, dim3(32768), dim3(256), 0, stream, logits, gamma, beta, xln);
    hipLaunchKernelGGL(qkv_kernel, dim3(1024, 6), dim3(256), 0, stream, xln, Wqt, qkvb);
    hipLaunchKernelGGL(attn_kernel, dim3(3072), dim3(512), 0, stream, qkvb, attnout);
    hipLaunchKernelGGL(proj_kernel, dim3(1024, 3), dim3(256), 0, stream, attnout, Wpt, bproj, out);
}

// Round 23
// 399.333 us; speedup vs baseline: 1.0746x; 1.0746x over previous
//
#include <hip/hip_runtime.h>

typedef __attribute__((ext_vector_type(8))) short bf16x8;
typedef __attribute__((ext_vector_type(4))) float f32x4;
typedef __attribute__((ext_vector_type(4))) unsigned int u32x4;
typedef __attribute__((ext_vector_type(2))) unsigned int u32x2;
typedef unsigned short u16;
typedef unsigned int u32;

__device__ __forceinline__ u16 f2bf(float f) {
    union { float f; u32 u; } c; c.f = f;
    return (u16)((c.u + 0x7FFFu + ((c.u >> 16) & 1u)) >> 16);
}

__device__ __forceinline__ bf16x8 ld16(const void* p) {
    union { uint4 u; bf16x8 v; } c;
    c.u = *reinterpret_cast<const uint4*>(p);
    return c.v;
}

__device__ __forceinline__ u32 cvtpk(float lo, float hi) {
    u32 r;
    asm("v_cvt_pk_bf16_f32 %0, %1, %2" : "=v"(r) : "v"(lo), "v"(hi));
    return r;
}

// ---------------- prep: transpose weights to bf16, n-major k-contig ----------
__global__ void prep_kernel(const float* __restrict__ wqkv, const float* __restrict__ wproj,
                            u16* __restrict__ Wqt, u16* __restrict__ Wpt) {
    int idx = blockIdx.x * 256 + threadIdx.x;
    if (idx < 6 * 192 * 384) {
        int k = idx % 384;
        int n = idx / 384;
        int h = n / 192, dd = n % 192;
        Wqt[idx] = f2bf(wqkv[(h * 384 + k) * 192 + dd]);
    }
    if (idx < 384 * 384) {
        int k = idx % 384, n = idx / 384;
        Wpt[idx] = f2bf(wproj[k * 384 + n]);
    }
}

// ---------------- LayerNorm: (131072,384) f32 -> bf16 -----------------------
__global__ __launch_bounds__(256) void ln_kernel(const float* __restrict__ x,
                                                 const float* __restrict__ gamma,
                                                 const float* __restrict__ beta,
                                                 u16* __restrict__ xln) {
    int row = blockIdx.x * 4 + (threadIdx.x >> 6);
    int l = threadIdx.x & 63;
    const float* xr = x + (size_t)row * 384;
    float2 v[3];
    float s = 0.f, sq = 0.f;
#pragma unroll
    for (int i = 0; i < 3; ++i) {
        v[i] = *reinterpret_cast<const float2*>(xr + i * 128 + l * 2);
        s += v[i].x + v[i].y;
        sq += v[i].x * v[i].x + v[i].y * v[i].y;
    }
#pragma unroll
    for (int m = 1; m < 64; m <<= 1) {
        s += __shfl_xor(s, m, 64);
        sq += __shfl_xor(sq, m, 64);
    }
    float mean = s * (1.0f / 384.0f);
    float var = sq * (1.0f / 384.0f) - mean * mean;
    float rstd = rsqrtf(var + 1e-5f);
#pragma unroll
    for (int i = 0; i < 3; ++i) {
        int c = i * 128 + l * 2;
        float y0 = (v[i].x - mean) * rstd * gamma[c] + beta[c];
        float y1 = (v[i].y - mean) * rstd * gamma[c + 1] + beta[c + 1];
        u32 packed = (u32)f2bf(y0) | ((u32)f2bf(y1) << 16);
        *reinterpret_cast<u32*>(xln + (size_t)row * 384 + c) = packed;
    }
}

// ---------------- QKV GEMM: BK=32, 40KB LDS dbuf, (row>>1) swizzle ----------
// grid (1024, 6): x=mt, y=h. 256 thr, 4 waves, wave 64x96, 3 blocks/CU.
// NOTE: launch_bounds(256,4) triple-confirmed to spill; keep (256,3).
__global__ __launch_bounds__(256, 3) void qkv_kernel(const u16* __restrict__ xln,
                                                     const u16* __restrict__ Wqt,
                                                     u16* __restrict__ qkvout) {
    __shared__ u16 As[2][128 * 32];   // 2 x 8 KB
    __shared__ u16 Bs[2][192 * 32];   // 2 x 12 KB -> total 40 KB
    const int mt = blockIdx.x;
    const int h = blockIdx.y;
    const int t = threadIdx.x;
    const int l = t & 63, w = t >> 6;
    const int wm = w >> 1, wn = w & 1;
    const int l15 = l & 15, lq = l >> 4;
    const int rloc = l >> 2;
    const int m0 = mt * 128;
    const u16* Ag = xln + (size_t)m0 * 384;
    const u16* Bg = Wqt + (size_t)h * 192 * 384;
    f32x4 acc[4][6];
#pragma unroll
    for (int rg = 0; rg < 4; ++rg)
#pragma unroll
        for (int cg = 0; cg < 6; ++cg) acc[rg][cg] = (f32x4){0.f, 0.f, 0.f, 0.f};

    auto stage = [&](int kt, int buf) {
#pragma unroll
        for (int i = 0; i < 2; ++i) {
            int row = w * 32 + i * 16 + rloc;
            int ss = (l & 3) ^ ((row >> 1) & 3);
            __builtin_amdgcn_global_load_lds(Ag + (size_t)row * 384 + kt * 32 + ss * 8,
                                             &As[buf][(w * 32 + i * 16) * 32], 16, 0, 0);
        }
#pragma unroll
        for (int i = 0; i < 3; ++i) {
            int row = w * 48 + i * 16 + rloc;
            int ss = (l & 3) ^ ((row >> 1) & 3);
            __builtin_amdgcn_global_load_lds(Bg + (size_t)row * 384 + kt * 32 + ss * 8,
                                             &Bs[buf][(w * 48 + i * 16) * 32], 16, 0, 0);
        }
    };

    stage(0, 0);
    __syncthreads();

    for (int kt = 0; kt < 12; ++kt) {
        const int cur = kt & 1;
        if (kt < 11) stage(kt + 1, cur ^ 1);
        char* Ab = reinterpret_cast<char*>(As[cur]);
        char* Bb = reinterpret_cast<char*>(Bs[cur]);
        bf16x8 af[4], bf[6];
#pragma unroll
        for (int rg = 0; rg < 4; ++rg) {
            int row = wm * 64 + rg * 16 + l15;
            af[rg] = ld16(Ab + row * 64 + ((lq ^ ((row >> 1) & 3)) << 4));
        }
#pragma unroll
        for (int cg = 0; cg < 6; ++cg) {
            int row = wn * 96 + cg * 16 + l15;
            bf[cg] = ld16(Bb + row * 64 + ((lq ^ ((row >> 1) & 3)) << 4));
        }
#pragma unroll
        for (int rg = 0; rg < 4; ++rg)
#pragma unroll
            for (int cg = 0; cg < 6; ++cg)
                acc[rg][cg] = __builtin_amdgcn_mfma_f32_16x16x32_bf16(af[rg], bf[cg], acc[rg][cg], 0, 0, 0);
        __syncthreads();
    }
    const int b = m0 >> 8;
    const int s0 = m0 & 255;
    u16* out = qkvout + ((size_t)(b * 6 + h) * 256) * 192;
#pragma unroll
    for (int rg = 0; rg < 4; ++rg)
#pragma unroll
        for (int cg = 0; cg < 6; ++cg)
#pragma unroll
            for (int r = 0; r < 4; ++r) {
                int s = s0 + wm * 64 + rg * 16 + lq * 4 + r;
                int dd = wn * 96 + cg * 16 + l15;
                out[(size_t)s * 192 + dd] = f2bf(acc[rg][cg][r]);
            }
}

// ---------------- Attention: swapped QK^T, in-register P pack (round-16) ----
__global__ __launch_bounds__(512, 2) void attn_kernel(const u16* __restrict__ qkv,
                                                      u16* __restrict__ aout) {
    __shared__ u16 Ks[256 * 64];      // 32 KB
    __shared__ u16 Vt[64 * 256];      // 32 KB
    __shared__ u16 Ps[8 * 16 * 32];   // 8 KB -> total 72 KB
    const int bh = blockIdx.x;
    const int b = bh / 6, h = bh % 6;
    const u16* base = qkv + (size_t)bh * (256 * 192);
    const int t = threadIdx.x;
    const int w = t >> 6, l = t & 63;
    const int l15 = l & 15, lq = l >> 4;

#pragma unroll
    for (int i = 0; i < 4; ++i) {
        int u = t + 512 * i;
        int row = u >> 3, seg = u & 7;
        uint4 v = *reinterpret_cast<const uint4*>(base + row * 192 + 64 + seg * 8);
        *reinterpret_cast<uint4*>(reinterpret_cast<char*>(Ks) + row * 128 + ((seg * 16) ^ ((row & 7) << 4))) = v;
    }
    {
        int j = t >> 1, d0 = (t & 1) * 32;
#pragma unroll
        for (int c = 0; c < 4; ++c) {
            uint4 v = *reinterpret_cast<const uint4*>(base + j * 192 + 128 + d0 + c * 8);
            const u16* pv = reinterpret_cast<const u16*>(&v);
#pragma unroll
            for (int e = 0; e < 8; ++e) {
                int d = d0 + c * 8 + e;
                *reinterpret_cast<u16*>(reinterpret_cast<char*>(Vt) + d * 512 + ((j * 2) ^ ((d & 7) << 4))) = pv[e];
            }
        }
    }
    const int qrow0 = w * 16;
    const int qrow1 = (15 - w) * 16;
    const int kbmax0 = w >> 2;
    const int kbmax1 = (15 - w) >> 2;
    bf16x8 qf[2][2];
#pragma unroll
    for (int kk = 0; kk < 2; ++kk) {
        qf[0][kk] = ld16(base + (qrow0 + l15) * 192 + kk * 32 + lq * 8);
        qf[1][kk] = ld16(base + (qrow1 + l15) * 192 + kk * 32 + lq * 8);
    }
    __syncthreads();

    f32x4 acc[2][4];
#pragma unroll
    for (int rg = 0; rg < 2; ++rg)
#pragma unroll
        for (int dg = 0; dg < 4; ++dg) acc[rg][dg] = (f32x4){0.f, 0.f, 0.f, 0.f};
    float l_r[2] = {0.f, 0.f};

    const float CEXP = 0.18033688011112042f;  // 0.125 * log2(e)
    char* pbase = reinterpret_cast<char*>(Ps) + w * 1024;
    auto fs = [](int row) { return ((row + (row >> 2)) & 3) << 4; };
    const int myfs = fs(l15);

    for (int kb = 0; kb <= kbmax1; ++kb) {
        const bool do0 = (kb <= kbmax0);
        f32x4 sc[2][4];
#pragma unroll
        for (int rg = 0; rg < 2; ++rg)
#pragma unroll
            for (int cg = 0; cg < 4; ++cg) sc[rg][cg] = (f32x4){0.f, 0.f, 0.f, 0.f};
#pragma unroll
        for (int kk = 0; kk < 2; ++kk) {
            bf16x8 kf[4];
#pragma unroll
            for (int cg = 0; cg < 4; ++cg) {
                int krow = kb * 64 + cg * 16 + l15;
                kf[cg] = ld16(reinterpret_cast<char*>(Ks) + krow * 128 + ((kk * 64 + lq * 16) ^ ((krow & 7) << 4)));
            }
            if (do0)
#pragma unroll
                for (int cg = 0; cg < 4; ++cg)
                    sc[0][cg] = __builtin_amdgcn_mfma_f32_16x16x32_bf16(kf[cg], qf[0][kk], sc[0][cg], 0, 0, 0);
#pragma unroll
            for (int cg = 0; cg < 4; ++cg)
                sc[1][cg] = __builtin_amdgcn_mfma_f32_16x16x32_bf16(kf[cg], qf[1][kk], sc[1][cg], 0, 0, 0);
        }
#pragma unroll
        for (int rg = 0; rg < 2; ++rg) {
            if (rg == 0 && !do0) continue;
            const int qb = rg ? qrow1 : qrow0;
            const int diag = rg ? kbmax1 : kbmax0;
            if (kb == diag) {
                int gq = qb + l15;
#pragma unroll
                for (int cg = 0; cg < 4; ++cg)
#pragma unroll
                    for (int r = 0; r < 4; ++r) {
                        int gk = kb * 64 + cg * 16 + lq * 4 + r;
                        if (gk > gq) sc[rg][cg][r] = -3.0e38f;
                    }
            }
#pragma unroll
            for (int cg = 0; cg < 4; ++cg)
#pragma unroll
                for (int r = 0; r < 4; ++r)
                    sc[rg][cg][r] = exp2f(sc[rg][cg][r] * CEXP);
            float s = ((sc[rg][0][0] + sc[rg][0][1]) + (sc[rg][0][2] + sc[rg][0][3]))
                    + ((sc[rg][1][0] + sc[rg][1][1]) + (sc[rg][1][2] + sc[rg][1][3]))
                    + ((sc[rg][2][0] + sc[rg][2][1]) + (sc[rg][2][2] + sc[rg][2][3]))
                    + ((sc[rg][3][0] + sc[rg][3][1]) + (sc[rg][3][2] + sc[rg][3][3]));
            s += __shfl_xor(s, 16, 64);
            s += __shfl_xor(s, 32, 64);
            l_r[rg] += s;
            u32 pk0[4], pk1[4];
#pragma unroll
            for (int cg = 0; cg < 4; ++cg) {
                pk0[cg] = cvtpk(sc[rg][cg][0], sc[rg][cg][1]);
                pk1[cg] = cvtpk(sc[rg][cg][2], sc[rg][cg][3]);
            }
#pragma unroll
            for (int kk = 0; kk < 2; ++kk) {
#pragma unroll
                for (int c2 = 0; c2 < 2; ++c2) {
                    int cg = kk * 2 + c2;
                    u32x2 wv;
                    wv.x = pk0[cg];
                    wv.y = pk1[cg];
                    *reinterpret_cast<u32x2*>(pbase + l15 * 64 + ((c2 * 32 + lq * 8) ^ myfs)) = wv;
                }
                bf16x8 pf = ld16(pbase + l15 * 64 + ((lq * 16) ^ myfs));
                bf16x8 vf[4];
#pragma unroll
                for (int dg = 0; dg < 4; ++dg) {
                    int d = dg * 16 + l15;
                    vf[dg] = ld16(reinterpret_cast<char*>(Vt) + d * 512 + ((kb * 128 + kk * 64 + lq * 16) ^ ((d & 7) << 4)));
                }
#pragma unroll
                for (int dg = 0; dg < 4; ++dg)
                    acc[rg][dg] = __builtin_amdgcn_mfma_f32_16x16x32_bf16(pf, vf[dg], acc[rg][dg], 0, 0, 0);
            }
        }
    }
#pragma unroll
    for (int rg = 0; rg < 2; ++rg) {
        const int qb = rg ? qrow1 : qrow0;
#pragma unroll
        for (int r = 0; r < 4; ++r) {
            float lr = __shfl(l_r[rg], lq * 4 + r, 64);
            float inv = 1.0f / lr;
            int gq = qb + lq * 4 + r;
            u16* orow = aout + ((size_t)b * 256 + gq) * 384 + h * 64;
#pragma unroll
            for (int dg = 0; dg < 4; ++dg) orow[dg * 16 + l15] = f2bf(acc[rg][dg][r] * inv);
        }
    }
}

// ---------------- Proj GEMM: gload_lds 2-phase + LDS-assembled nt epilogue --
__global__ __launch_bounds__(256, 2) void proj_kernel(const u16* __restrict__ A,
                                                      const u16* __restrict__ Wpt,
                                                      const float* __restrict__ bias,
                                                      float* __restrict__ out) {
    __shared__ u16 S[32768];  // 64 KB: As dbuf 2x8192, Bs dbuf 2x8192
    u16* Asb[2] = {S, S + 8192};
    u16* Bsb[2] = {S + 16384, S + 24576};
    const int mt = blockIdx.x;
    const int nt = blockIdx.y;
    const int t = threadIdx.x;
    const int l = t & 63, w = t >> 6;
    const int wm = w >> 1, wn = w & 1;
    const int l15 = l & 15, lq = l >> 4;
    const int rloc = l >> 3, seg = l & 7;
    const int m0 = mt * 128;
    const u16* Ag = A + (size_t)m0 * 384;
    const u16* Bg = Wpt + (size_t)nt * 128 * 384;
    f32x4 acc[4][4];
#pragma unroll
    for (int rg = 0; rg < 4; ++rg)
#pragma unroll
        for (int cg = 0; cg < 4; ++cg) acc[rg][cg] = (f32x4){0.f, 0.f, 0.f, 0.f};

    auto stage = [&](int kt, int buf) {
#pragma unroll
        for (int i = 0; i < 4; ++i) {
            int row = w * 32 + i * 8 + rloc;
            int ss = seg ^ (row & 7);
            __builtin_amdgcn_global_load_lds(Ag + (size_t)row * 384 + kt * 64 + ss * 8,
                                             &Asb[buf][(w * 32 + i * 8) * 64], 16, 0, 0);
            __builtin_amdgcn_global_load_lds(Bg + (size_t)row * 384 + kt * 64 + ss * 8,
                                             &Bsb[buf][(w * 32 + i * 8) * 64], 16, 0, 0);
        }
    };

    stage(0, 0);
    __syncthreads();

    for (int kt = 0; kt < 6; ++kt) {
        const int cur = kt & 1;
        if (kt < 5) stage(kt + 1, cur ^ 1);
        char* Ab = reinterpret_cast<char*>(Asb[cur]);
        char* Bb = reinterpret_cast<char*>(Bsb[cur]);
        bf16x8 af[4][2], bf[4][2];
#pragma unroll
        for (int rg = 0; rg < 4; ++rg)
#pragma unroll
            for (int kk = 0; kk < 2; ++kk) {
                int row = wm * 64 + rg * 16 + l15;
                af[rg][kk] = ld16(Ab + row * 128 + ((kk * 64 + lq * 16) ^ ((row & 7) << 4)));
            }
#pragma unroll
        for (int cg = 0; cg < 4; ++cg)
#pragma unroll
            for (int kk = 0; kk < 2; ++kk) {
                int row = wn * 64 + cg * 16 + l15;
                bf[cg][kk] = ld16(Bb + row * 128 + ((kk * 64 + lq * 16) ^ ((row & 7) << 4)));
            }
#pragma unroll
        for (int kk = 0; kk < 2; ++kk)
#pragma unroll
            for (int rg = 0; rg < 4; ++rg)
#pragma unroll
                for (int cg = 0; cg < 4; ++cg)
                    acc[rg][cg] = __builtin_amdgcn_mfma_f32_16x16x32_bf16(af[rg][kk], bf[cg][kk], acc[rg][cg], 0, 0, 0);
        __syncthreads();
    }
    float* ftile = reinterpret_cast<float*>(S);
#pragma unroll
    for (int rg = 0; rg < 4; ++rg)
#pragma unroll
        for (int cg = 0; cg < 4; ++cg) {
            int n_loc = wn * 64 + cg * 16 + l15;
            float bv = bias[nt * 128 + n_loc];
#pragma unroll
            for (int r = 0; r < 4; ++r) {
                int m_loc = wm * 64 + rg * 16 + lq * 4 + r;
                ftile[m_loc * 128 + n_loc] = acc[rg][cg][r] + bv;
            }
        }
    __syncthreads();
    float* outp = out + (size_t)m0 * 384 + nt * 128;
#pragma unroll
    for (int i = 0; i < 16; ++i) {
        int idx = t + 256 * i;
        int row = idx >> 5;
        int c = (idx & 31) * 4;
        u32x4 v = *reinterpret_cast<const u32x4*>(ftile + row * 128 + c);
        __builtin_nontemporal_store(v, reinterpret_cast<u32x4*>(outp + (size_t)row * 384 + c));
    }
}

extern "C" void kernel_launch(void* const* d_in, const int* in_sizes, int n_in,
                              void* d_out, int out_size, void* d_ws, size_t ws_size,
                              hipStream_t stream) {
    const float* logits = (const float*)d_in[0];
    const float* gamma  = (const float*)d_in[1];
    const float* beta   = (const float*)d_in[2];
    const float* wqkv   = (const float*)d_in[3];
    const float* wproj  = (const float*)d_in[4];
    const float* bproj  = (const float*)d_in[5];
    float* out = (float*)d_out;

    char* ws = (char*)d_ws;
    u16* Wqt  = (u16*)(ws);                    //   884736 B
    u16* Wpt  = (u16*)(ws + 884736);           //   294912 B
    u16* xln  = (u16*)(ws + 1179648);          // 100663296 B
    u16* qkvb = (u16*)(ws + 101842944);        // 301989888 B -> total 403832832 B
    u16* attnout = xln;                        // alias: xln dead after qkv gemm

    hipLaunchKernelGGL(prep_kernel, dim3(1728), dim3(256), 0, stream, wqkv, wproj, Wqt, Wpt);
    hipLaunchKernelGGL(ln_kernel, dim3(32768), dim3(256), 0, stream, logits, gamma, beta, xln);
    hipLaunchKernelGGL(qkv_kernel, dim3(1024, 6), dim3(256), 0, stream, xln, Wqt, qkvb);
    hipLaunchKernelGGL(attn_kernel, dim3(3072), dim3(512), 0, stream, qkvb, attnout);
    hipLaunchKernelGGL(proj_kernel, dim3(1024, 3), dim3(256), 0, stream, attnout, Wpt, bproj, out);
}